// Round 5
// baseline (455.798 us; speedup 1.0000x reference)
//
#include <hip/hip_runtime.h>
#include <math.h>

#define B_ 32
#define HW_ 4096
#define N_ 16
#define C_ 128
#define F_ 512
#define ITERS_ 3
#define EPS_LN 1e-5f
#define EPS_ATTN 1e-5f

typedef __attribute__((ext_vector_type(8))) short short8;
typedef __attribute__((ext_vector_type(4))) float f32x4;

static __device__ __forceinline__ unsigned short f2b(float f) {
    union { float f; unsigned u; } v; v.f = f;
    unsigned r = v.u + 0x7fffu + ((v.u >> 16) & 1u);
    return (unsigned short)(r >> 16);
}
static __device__ __forceinline__ float blo(unsigned u) {
    union { unsigned u; float f; } v; v.u = u << 16; return v.f;
}
static __device__ __forceinline__ float bhi(unsigned u) {
    union { unsigned u; float f; } v; v.u = u & 0xffff0000u; return v.f;
}

// ---------------------------------------------------------------------------
// One-time prep: blocks 0..255 convert weights fp32->bf16; blocks 256..287
// compute qn_0 = (LN(query)*g+b) @ Wq^T * scale.
// ---------------------------------------------------------------------------
__global__ __launch_bounds__(256) void k_prep(
    const float* __restrict__ Wk, const float* __restrict__ Wv,
    const float* __restrict__ wih, const float* __restrict__ whh,
    const float* __restrict__ w1, const float* __restrict__ w2,
    unsigned short* __restrict__ Wk_bf, unsigned short* __restrict__ Wv_bf,
    unsigned short* __restrict__ wih_bf, unsigned short* __restrict__ whh_bf,
    unsigned short* __restrict__ w1_bf, unsigned short* __restrict__ w2_bf,
    const float* __restrict__ query, const float* __restrict__ lnqg,
    const float* __restrict__ lnqb, const float* __restrict__ Wq,
    unsigned short* __restrict__ qn_g)
{
    __shared__ __align__(16) float xq[16 * 128];
    int tid = threadIdx.x;
    if (blockIdx.x < 256) {
        int t = blockIdx.x * 256 + tid;
        const float* src; unsigned short* dst; int off;
        if (t < 4096)       { src = Wk;  dst = Wk_bf;  off = t; }
        else if (t < 8192)  { src = Wv;  dst = Wv_bf;  off = t - 4096; }
        else if (t < 20480) { src = wih; dst = wih_bf; off = t - 8192; }
        else if (t < 32768) { src = whh; dst = whh_bf; off = t - 20480; }
        else if (t < 49152) { src = w1;  dst = w1_bf;  off = t - 32768; }
        else                { src = w2;  dst = w2_bf;  off = t - 49152; }
        float4 a = ((const float4*)src)[off];
        uint2 p;
        p.x = (unsigned)f2b(a.x) | ((unsigned)f2b(a.y) << 16);
        p.y = (unsigned)f2b(a.z) | ((unsigned)f2b(a.w) << 16);
        *(uint2*)(dst + off * 4) = p;
        return;
    }
    int b = blockIdx.x - 256;
    int n = tid >> 4, part = tid & 15;
    int row = b * 16 + n;
    const float4* x4 = (const float4*)(query + row * 128 + part * 8);
    float4 x0 = x4[0], x1 = x4[1];
    float s = x0.x + x0.y + x0.z + x0.w + x1.x + x1.y + x1.z + x1.w;
    float ss = x0.x * x0.x + x0.y * x0.y + x0.z * x0.z + x0.w * x0.w +
               x1.x * x1.x + x1.y * x1.y + x1.z * x1.z + x1.w * x1.w;
    s += __shfl_xor(s, 1); s += __shfl_xor(s, 2); s += __shfl_xor(s, 4); s += __shfl_xor(s, 8);
    ss += __shfl_xor(ss, 1); ss += __shfl_xor(ss, 2); ss += __shfl_xor(ss, 4); ss += __shfl_xor(ss, 8);
    float mean = s * (1.f / 128.f);
    float var = ss * (1.f / 128.f) - mean * mean;
    float rstd = rsqrtf(var + EPS_LN);
    const float4* g4 = (const float4*)(lnqg + part * 8);
    const float4* b4 = (const float4*)(lnqb + part * 8);
    float4 g0 = g4[0], g1 = g4[1], bb0 = b4[0], bb1 = b4[1];
    float4 o0, o1;
    o0.x = (x0.x - mean) * rstd * g0.x + bb0.x;
    o0.y = (x0.y - mean) * rstd * g0.y + bb0.y;
    o0.z = (x0.z - mean) * rstd * g0.z + bb0.z;
    o0.w = (x0.w - mean) * rstd * g0.w + bb0.w;
    o1.x = (x1.x - mean) * rstd * g1.x + bb1.x;
    o1.y = (x1.y - mean) * rstd * g1.y + bb1.y;
    o1.z = (x1.z - mean) * rstd * g1.z + bb1.z;
    o1.w = (x1.w - mean) * rstd * g1.w + bb1.w;
    float4* xrow = (float4*)&xq[n * 128];
    xrow[part * 2] = o0;
    xrow[part * 2 + 1] = o1;
    __syncthreads();
    float o[8] = {0.f, 0.f, 0.f, 0.f, 0.f, 0.f, 0.f, 0.f};
    const float4* xv4 = (const float4*)&xq[n * 128];
#pragma unroll 4
    for (int j = 0; j < 32; j++) {
        float4 xv = xv4[j];
#pragma unroll
        for (int i = 0; i < 8; i++) {
            float4 w = ((const float4*)(Wq + (part * 8 + i) * 128))[j];
            o[i] += w.x * xv.x + w.y * xv.y + w.z * xv.z + w.w * xv.w;
        }
    }
    const float scale = 0.08838834764831845f;
#pragma unroll
    for (int i = 0; i < 8; i++)
        qn_g[row * 128 + part * 8 + i] = f2b(o[i] * scale);
}

// ---------------------------------------------------------------------------
// Kernel 1: kv = LN(inp); blocks 0..511: K = kv@Wk^T -> [b][hw][c];
// blocks 512..1023: V -> transposed [b][c][hw]. 4 tiles of 64 rows per block,
// W staged ONCE per block (1 barrier), in-register LN, direct packed stores
// from MFMA acc (operand order chosen so each lane holds 4 consecutive
// output elements). No T staging, no per-tile barriers.
// ---------------------------------------------------------------------------
__global__ __launch_bounds__(256) void k_kvproj(
    const float* __restrict__ inp, const float* __restrict__ lng,
    const float* __restrict__ lnb, const unsigned short* __restrict__ Wk_bf,
    const unsigned short* __restrict__ Wv_bf, unsigned short* __restrict__ Kbf,
    unsigned short* __restrict__ Vt)
{
    __shared__ __align__(16) unsigned short W_lds[128 * 128];  // 32 KB
    const int tid = threadIdx.x;
    const int wave = tid >> 6, lane = tid & 63;
    const int l15 = lane & 15, q4 = lane >> 4;
    const int kof = q4 * 8;
    const int isK = (blockIdx.x < 512);
    const int blkL = blockIdx.x & 511;

    // ---- stage W (swizzled), once per block ----
    {
        const unsigned short* Wsrc = isK ? Wk_bf : Wv_bf;
        int srow = tid >> 1, shalf = tid & 1, sswz = srow & 7;
        const uint4* gW = (const uint4*)Wsrc;
#pragma unroll
        for (int j = 0; j < 8; j++) {
            int c = shalf * 8 + j;
            *(uint4*)&W_lds[srow * 128 + (c ^ sswz) * 8] = gW[srow * 16 + c];
        }
    }
    __syncthreads();

#pragma unroll 1
    for (int t = 0; t < 4; t++) {
        const int tile0 = (blkL * 4 + t) * 64;
        const int b = tile0 >> 12;
        const int hwbase = tile0 & (HW_ - 1);

        // ---- in-register LN for row = tile0 + wave*16 + l15 ----
        float x[4][8];
        {
            const float* rowp = inp + (tile0 + (wave << 4) + l15) * C_;
            float s = 0.f, ss = 0.f;
#pragma unroll
            for (int ks = 0; ks < 4; ks++) {
#pragma unroll
                for (int h = 0; h < 2; h++) {
                    float4 v = *(const float4*)(rowp + ks * 32 + kof + h * 4);
                    x[ks][h * 4 + 0] = v.x; x[ks][h * 4 + 1] = v.y;
                    x[ks][h * 4 + 2] = v.z; x[ks][h * 4 + 3] = v.w;
                    s += v.x + v.y + v.z + v.w;
                    ss += v.x * v.x + v.y * v.y + v.z * v.z + v.w * v.w;
                }
            }
            s += __shfl_xor(s, 16);  s += __shfl_xor(s, 32);
            ss += __shfl_xor(ss, 16); ss += __shfl_xor(ss, 32);
            float mean = s * (1.f / 128.f);
            float var = ss * (1.f / 128.f) - mean * mean;
            float rstd = rsqrtf(var + EPS_LN);
#pragma unroll
            for (int ks = 0; ks < 4; ks++) {
#pragma unroll
                for (int h = 0; h < 2; h++) {
                    float4 g = *(const float4*)(lng + ks * 32 + kof + h * 4);
                    float4 bb = *(const float4*)(lnb + ks * 32 + kof + h * 4);
                    x[ks][h * 4 + 0] = (x[ks][h * 4 + 0] - mean) * rstd * g.x + bb.x;
                    x[ks][h * 4 + 1] = (x[ks][h * 4 + 1] - mean) * rstd * g.y + bb.y;
                    x[ks][h * 4 + 2] = (x[ks][h * 4 + 2] - mean) * rstd * g.z + bb.z;
                    x[ks][h * 4 + 3] = (x[ks][h * 4 + 3] - mean) * rstd * g.w + bb.w;
                }
            }
        }
        short8 af[4];
#pragma unroll
        for (int ks = 0; ks < 4; ks++) {
            union { short8 s8; unsigned u[4]; } p;
#pragma unroll
            for (int j = 0; j < 4; j++)
                p.u[j] = (unsigned)f2b(x[ks][2 * j]) | ((unsigned)f2b(x[ks][2 * j + 1]) << 16);
            af[ks] = p.s8;
        }

        if (isK) {
            // D = W x kv : lane holds (row = l15, c = ct*16 + q4*4 + 0..3)
#pragma unroll
            for (int ct = 0; ct < 8; ct++) {
                f32x4 acc = {0.f, 0.f, 0.f, 0.f};
#pragma unroll
                for (int ks = 0; ks < 4; ks++) {
                    short8 wf = *(const short8*)&W_lds[(ct * 16 + l15) * 128 + ((ks * 4 + q4) ^ (l15 & 7)) * 8];
                    acc = __builtin_amdgcn_mfma_f32_16x16x32_bf16(wf, af[ks], acc, 0, 0, 0);
                }
                union { uint2 u2; unsigned short sh[4]; } pk;
#pragma unroll
                for (int i = 0; i < 4; i++) pk.sh[i] = f2b(acc[i]);
                *(uint2*)&Kbf[(b * HW_ + hwbase + (wave << 4) + l15) * C_ + ct * 16 + (q4 << 2)] = pk.u2;
            }
        } else {
            // D = kv x W : lane holds (c = nt*16 + l15, hw = base + q4*4 + 0..3)
#pragma unroll
            for (int nt = 0; nt < 8; nt++) {
                f32x4 acc = {0.f, 0.f, 0.f, 0.f};
#pragma unroll
                for (int ks = 0; ks < 4; ks++) {
                    short8 wf = *(const short8*)&W_lds[(nt * 16 + l15) * 128 + ((ks * 4 + q4) ^ (l15 & 7)) * 8];
                    acc = __builtin_amdgcn_mfma_f32_16x16x32_bf16(af[ks], wf, acc, 0, 0, 0);
                }
                union { uint2 u2; unsigned short sh[4]; } pv;
#pragma unroll
                for (int i = 0; i < 4; i++) pv.sh[i] = f2b(acc[i]);
                *(uint2*)&Vt[(b * C_ + nt * 16 + l15) * HW_ + hwbase + (wave << 4) + (q4 << 2)] = pv.u2;
            }
        }
    }
}

// ---------------------------------------------------------------------------
// Kernel 2 (per iter): logits -> column softmax (16 slots) -> a0 ->
// LDS-atomic U accumulation -> per-chunk partial U [q*128+c] / rowsum.
// grid (32, B): 128 hw/block, 32 hw/wave. LDS ~14.5 KB -> 8 blocks/CU.
// ---------------------------------------------------------------------------
__global__ __launch_bounds__(256) void k_attn(
    const unsigned short* __restrict__ qn_g, const unsigned short* __restrict__ Kbf,
    const unsigned short* __restrict__ Vt, float* __restrict__ Upart,
    float* __restrict__ rspart, float* __restrict__ a0_out, int last)
{
    __shared__ float Ul[16 * 137];                      // 8768 B, stride-137 pad
    __shared__ __align__(16) unsigned short Pb[4][16 * 40];
    __shared__ float rsw[4][16];
    const int b = blockIdx.y, chunk = blockIdx.x;
    const int tid = threadIdx.x;
    const int wave = tid >> 6, lane = tid & 63;
    const int l15 = lane & 15, q4 = lane >> 4;
    const int kof = q4 * 8;
    const int hwb = chunk * 128 + wave * 32;

    // zero the shared accumulator
    for (int i = tid; i < 16 * 137; i += 256) Ul[i] = 0.f;

    short8 aq[4];
#pragma unroll
    for (int ks = 0; ks < 4; ks++)
        aq[ks] = *(const short8*)&qn_g[(b * 16 + l15) * 128 + ks * 32 + kof];
    // preload independent Vt A-frags
    short8 av[8];
#pragma unroll
    for (int ct = 0; ct < 8; ct++)
        av[ct] = *(const short8*)&Vt[(b * C_ + ct * 16 + l15) * HW_ + hwb + kof];
    __syncthreads();   // zero-init complete

    unsigned short* Pw = &Pb[wave][0];
    float rs[4] = {0.f, 0.f, 0.f, 0.f};
#pragma unroll
    for (int s = 0; s < 2; s++) {
        int hwt = hwb + s * 16;
        f32x4 sa = {0.f, 0.f, 0.f, 0.f};
#pragma unroll
        for (int ks = 0; ks < 4; ks++) {
            short8 bk = *(const short8*)&Kbf[(b * HW_ + hwt + l15) * C_ + ks * 32 + kof];
            sa = __builtin_amdgcn_mfma_f32_16x16x32_bf16(aq[ks], bk, sa, 0, 0, 0);
        }
        float mx = fmaxf(fmaxf(sa[0], sa[1]), fmaxf(sa[2], sa[3]));
        mx = fmaxf(mx, __shfl_xor(mx, 16));
        mx = fmaxf(mx, __shfl_xor(mx, 32));
        float e[4]; float ssum = 0.f;
#pragma unroll
        for (int i = 0; i < 4; i++) { e[i] = __expf(sa[i] - mx); ssum += e[i]; }
        ssum += __shfl_xor(ssum, 16);
        ssum += __shfl_xor(ssum, 32);
        float inv = 1.f / ssum;
#pragma unroll
        for (int i = 0; i < 4; i++) {
            float a0v = e[i] * inv;
            rs[i] += a0v;
            if (last) a0_out[(b * 16 + q4 * 4 + i) * HW_ + hwt + l15] = a0v;
            Pw[(q4 * 4 + i) * 40 + s * 16 + l15] = f2b(a0v);
        }
    }
#pragma unroll
    for (int i = 0; i < 4; i++) {
        rs[i] += __shfl_xor(rs[i], 1);
        rs[i] += __shfl_xor(rs[i], 2);
        rs[i] += __shfl_xor(rs[i], 4);
        rs[i] += __shfl_xor(rs[i], 8);
    }
    if (l15 == 0) {
#pragma unroll
        for (int i = 0; i < 4; i++) rsw[wave][q4 * 4 + i] = rs[i];
    }
    // u MFMA: lane holds (q = l15, c = ct*16 + q4*4 + i) -> ds_add into Ul[q][c]
    short8 bp = *(const short8*)&Pw[l15 * 40 + kof];
#pragma unroll
    for (int ct = 0; ct < 8; ct++) {
        f32x4 ua = __builtin_amdgcn_mfma_f32_16x16x32_bf16(av[ct], bp, (f32x4){0.f, 0.f, 0.f, 0.f}, 0, 0, 0);
        int c = ct * 16 + (q4 << 2);
#pragma unroll
        for (int i = 0; i < 4; i++)
            atomicAdd(&Ul[l15 * 137 + c + i], ua[i]);
    }
    __syncthreads();
    {
        float* up = Upart + (b * 32 + chunk) * 2048;
#pragma unroll
        for (int k = 0; k < 8; k++) {
            int idx = tid + k * 256;          // idx = q*128 + c
            up[idx] = Ul[(idx >> 7) * 137 + (idx & 127)];
        }
        if (tid < 16)
            rspart[(b * 32 + chunk) * 16 + tid] =
                rsw[0][tid] + rsw[1][tid] + rsw[2][tid] + rsw[3][tid];
    }
}

// ---------------------------------------------------------------------------
// Kernel 3 (per iter): one (b,q) row per block, 256 threads.
// u = (sum Upart)/(sum rspart + eps); y = GRU(u, h); z = LN2(y);
// q_new = y + FFN(z); if !last: qn_next = LN(q_new)@Wq^T*scale.
// ---------------------------------------------------------------------------
__global__ __launch_bounds__(256) void k_tail(
    const float* __restrict__ Upart, const float* __restrict__ rspart,
    const float* __restrict__ hsrc, float* __restrict__ q_buf,
    const unsigned short* __restrict__ wih_bf, const unsigned short* __restrict__ whh_bf,
    const float* __restrict__ bih, const float* __restrict__ bhh,
    const float* __restrict__ ln2g, const float* __restrict__ ln2b,
    const unsigned short* __restrict__ w1_bf, const float* __restrict__ b1,
    const unsigned short* __restrict__ w2_bf, const float* __restrict__ b2,
    const float* __restrict__ lnqg, const float* __restrict__ lnqb,
    const float* __restrict__ Wq, unsigned short* __restrict__ qn_g,
    float* __restrict__ out_q, int last)
{
    __shared__ __align__(16) float u_l[128];
    __shared__ __align__(16) float h_l[128];
    __shared__ __align__(16) float g_l[768];
    __shared__ __align__(16) float z_l[128];
    __shared__ __align__(16) float y_l[128];
    __shared__ __align__(16) float h1_l[512];
    __shared__ __align__(16) float red[256];
    __shared__ float stats[2];
    __shared__ float srs;
    const int tid = threadIdx.x;
    const int row = blockIdx.x;
    const int b = row >> 4, q = row & 15;
    const int lane = tid & 63;

    // coalesced Upart reduce: thread (c = tid&127, h = tid>>7) sums 16 chunks
    {
        int c = tid & 127, h = tid >> 7;
        float part = 0.f;
#pragma unroll
        for (int ch = 0; ch < 16; ch++)
            part += Upart[(b * 32 + h * 16 + ch) * 2048 + q * 128 + c];
        red[tid] = part;
        if (tid < 128) h_l[tid] = hsrc[row * 128 + tid];
        if (tid < 64) {
            float v = (lane < 32) ? rspart[(b * 32 + lane) * 16 + q] : 0.f;
#pragma unroll
            for (int off = 1; off < 64; off <<= 1) v += __shfl_xor(v, off);
            if (tid == 0) srs = v;
        }
    }
    __syncthreads();
    if (tid < 128)
        u_l[tid] = (red[tid] + red[tid + 128]) / (srs + EPS_ATTN);
    __syncthreads();
    // GRU gates: 768 outputs, 3 per thread
#pragma unroll
    for (int o3 = 0; o3 < 3; o3++) {
        int o = tid + o3 * 256;
        const unsigned short* wrow;
        const float* src;
        float bias;
        if (o < 384) { wrow = wih_bf + o * 128; src = u_l; bias = bih[o]; }
        else         { wrow = whh_bf + (o - 384) * 128; src = h_l; bias = bhh[o - 384]; }
        const uint4* w4 = (const uint4*)wrow;
        const float4* s4 = (const float4*)src;
        float acc = 0.f;
#pragma unroll 8
        for (int j = 0; j < 16; j++) {
            uint4 w = w4[j];
            float4 aA = s4[2 * j], aB = s4[2 * j + 1];
            acc += blo(w.x) * aA.x + bhi(w.x) * aA.y + blo(w.y) * aA.z + bhi(w.y) * aA.w
                 + blo(w.z) * aB.x + bhi(w.z) * aB.y + blo(w.w) * aB.z + bhi(w.w) * aB.w;
        }
        g_l[o] = acc + bias;
    }
    __syncthreads();
    if (tid < 128) {
        int c = tid;
        float ir = g_l[c], iz = g_l[128 + c], in_ = g_l[256 + c];
        float hr = g_l[384 + c], hz = g_l[512 + c], hn = g_l[640 + c];
        float rr = 1.f / (1.f + expf(-(ir + hr)));
        float zz = 1.f / (1.f + expf(-(iz + hz)));
        float nn = tanhf(in_ + rr * hn);
        y_l[c] = (1.f - zz) * nn + zz * h_l[c];
    }
    __syncthreads();
    if (tid < 64) {
        float v0 = y_l[lane], v1 = y_l[lane + 64];
        float s = v0 + v1, ss = v0 * v0 + v1 * v1;
#pragma unroll
        for (int off = 1; off < 64; off <<= 1) {
            s += __shfl_xor(s, off);
            ss += __shfl_xor(ss, off);
        }
        if (tid == 0) {
            float mean = s * (1.f / 128.f);
            float var = ss * (1.f / 128.f) - mean * mean;
            stats[0] = mean;
            stats[1] = rsqrtf(var + EPS_LN);
        }
    }
    __syncthreads();
    if (tid < 128)
        z_l[tid] = (y_l[tid] - stats[0]) * stats[1] * ln2g[tid] + ln2b[tid];
    __syncthreads();
    // FFN1: 512 outputs, 2 per thread
#pragma unroll
    for (int f2i = 0; f2i < 2; f2i++) {
        int f = tid + f2i * 256;
        const uint4* w4 = (const uint4*)(w1_bf + f * 128);
        const float4* s4 = (const float4*)z_l;
        float acc = 0.f;
#pragma unroll 8
        for (int j = 0; j < 16; j++) {
            uint4 w = w4[j];
            float4 aA = s4[2 * j], aB = s4[2 * j + 1];
            acc += blo(w.x) * aA.x + bhi(w.x) * aA.y + blo(w.y) * aA.z + bhi(w.y) * aA.w
                 + blo(w.z) * aB.x + bhi(w.z) * aB.y + blo(w.w) * aB.z + bhi(w.w) * aB.w;
        }
        h1_l[f] = fmaxf(acc + b1[f], 0.f);
    }
    __syncthreads();
    // FFN2: thread (c = tid&127, h = tid>>7) computes half the 512-dot
    {
        int c = tid & 127, h = tid >> 7;
        const uint4* w4 = (const uint4*)(w2_bf + c * 512 + h * 256);
        const float4* hh = (const float4*)&h1_l[h * 256];
        float acc = 0.f;
#pragma unroll 8
        for (int j = 0; j < 32; j++) {
            uint4 w = w4[j];
            float4 hA = hh[2 * j], hB = hh[2 * j + 1];
            acc += blo(w.x) * hA.x + bhi(w.x) * hA.y + blo(w.y) * hA.z + bhi(w.y) * hA.w
                 + blo(w.z) * hB.x + bhi(w.z) * hB.y + blo(w.w) * hB.z + bhi(w.w) * hB.w;
        }
        red[tid] = acc;
    }
    __syncthreads();
    float q_new = 0.f;
    if (tid < 128) {
        q_new = y_l[tid] + red[tid] + red[tid + 128] + b2[tid];
        q_buf[row * 128 + tid] = q_new;
        if (last) out_q[row * 128 + tid] = q_new;
    }
    if (!last) {
        __syncthreads();
        if (tid < 128) y_l[tid] = q_new;
        __syncthreads();
        if (tid < 64) {
            float v0 = y_l[lane], v1 = y_l[lane + 64];
            float s = v0 + v1, ss = v0 * v0 + v1 * v1;
#pragma unroll
            for (int off = 1; off < 64; off <<= 1) {
                s += __shfl_xor(s, off);
                ss += __shfl_xor(ss, off);
            }
            if (tid == 0) {
                float mean = s * (1.f / 128.f);
                float var = ss * (1.f / 128.f) - mean * mean;
                stats[0] = mean;
                stats[1] = rsqrtf(var + EPS_LN);
            }
        }
        __syncthreads();
        if (tid < 128)
            z_l[tid] = (y_l[tid] - stats[0]) * stats[1] * lnqg[tid] + lnqb[tid];
        __syncthreads();
        {
            int c = tid & 127, h = tid >> 7;
            const float4* w4 = (const float4*)(Wq + c * 128 + h * 64);
            const float4* zz = (const float4*)&z_l[h * 64];
            float acc = 0.f;
#pragma unroll 8
            for (int j = 0; j < 16; j++) {
                float4 w = w4[j], v = zz[j];
                acc += w.x * v.x + w.y * v.y + w.z * v.z + w.w * v.w;
            }
            red[tid] = acc;
        }
        __syncthreads();
        if (tid < 128)
            qn_g[row * 128 + tid] = f2b((red[tid] + red[tid + 128]) * 0.08838834764831845f);
    }
}

// ---------------------------------------------------------------------------
extern "C" void kernel_launch(void* const* d_in, const int* in_sizes, int n_in,
                              void* d_out, int out_size, void* d_ws, size_t ws_size,
                              hipStream_t stream) {
    const float* inp     = (const float*)d_in[0];
    const float* query   = (const float*)d_in[1];
    const float* ln_kv_g = (const float*)d_in[2];
    const float* ln_kv_b = (const float*)d_in[3];
    const float* Wk      = (const float*)d_in[4];
    const float* Wv      = (const float*)d_in[5];
    const float* ln_q_g  = (const float*)d_in[6];
    const float* ln_q_b  = (const float*)d_in[7];
    const float* Wq      = (const float*)d_in[8];
    const float* gru_wih = (const float*)d_in[9];
    const float* gru_whh = (const float*)d_in[10];
    const float* gru_bih = (const float*)d_in[11];
    const float* gru_bhh = (const float*)d_in[12];
    const float* ln2_g   = (const float*)d_in[13];
    const float* ln2_b   = (const float*)d_in[14];
    const float* ffn_w1  = (const float*)d_in[15];
    const float* ffn_b1  = (const float*)d_in[16];
    const float* ffn_w2  = (const float*)d_in[17];
    const float* ffn_b2  = (const float*)d_in[18];

    char* ws = (char*)d_ws;
    unsigned short* Kbf    = (unsigned short*)ws;                  // 33554432
    unsigned short* Vt     = (unsigned short*)(ws + 33554432);     // 33554432
    float* q_buf           = (float*)(ws + 67108864);              // 262144
    float* Upart           = (float*)(ws + 67371008);              // 8388608
    float* rspart          = (float*)(ws + 75759616);              // 65536
    unsigned short* qn_g   = (unsigned short*)(ws + 75825152);     // 131072
    unsigned short* Wk_bf  = (unsigned short*)(ws + 75956224);     // 32768
    unsigned short* Wv_bf  = (unsigned short*)(ws + 75988992);     // 32768
    unsigned short* wih_bf = (unsigned short*)(ws + 76021760);     // 98304
    unsigned short* whh_bf = (unsigned short*)(ws + 76120064);     // 98304
    unsigned short* w1_bf  = (unsigned short*)(ws + 76218368);     // 131072
    unsigned short* w2_bf  = (unsigned short*)(ws + 76349440);     // 131072

    float* out_q  = (float*)d_out;
    float* out_a0 = out_q + B_ * N_ * C_;

    k_prep<<<dim3(288), dim3(256), 0, stream>>>(
        Wk, Wv, gru_wih, gru_whh, ffn_w1, ffn_w2,
        Wk_bf, Wv_bf, wih_bf, whh_bf, w1_bf, w2_bf,
        query, ln_q_g, ln_q_b, Wq, qn_g);
    k_kvproj<<<dim3(1024), dim3(256), 0, stream>>>(
        inp, ln_kv_g, ln_kv_b, Wk_bf, Wv_bf, Kbf, Vt);

    for (int it = 0; it < ITERS_; it++) {
        int last = (it == ITERS_ - 1) ? 1 : 0;
        const float* hsrc = (it == 0) ? query : q_buf;
        k_attn<<<dim3(32, B_), dim3(256), 0, stream>>>(
            qn_g, Kbf, Vt, Upart, rspart, out_a0, last);
        k_tail<<<dim3(B_ * N_), dim3(256), 0, stream>>>(
            Upart, rspart, hsrc, q_buf, wih_bf, whh_bf, gru_bih, gru_bhh,
            ln2_g, ln2_b, w1_bf, ffn_b1, w2_bf, ffn_b2,
            ln_q_g, ln_q_b, Wq, qn_g, out_q, last);
    }
}

// Round 6
// 332.350 us; speedup vs baseline: 1.3714x; 1.3714x over previous
//
#include <hip/hip_runtime.h>
#include <math.h>

#define B_ 32
#define HW_ 4096
#define N_ 16
#define C_ 128
#define F_ 512
#define ITERS_ 3
#define EPS_LN 1e-5f
#define EPS_ATTN 1e-5f

typedef __attribute__((ext_vector_type(8))) short short8;
typedef __attribute__((ext_vector_type(4))) float f32x4;

static __device__ __forceinline__ unsigned short f2b(float f) {
    union { float f; unsigned u; } v; v.f = f;
    unsigned r = v.u + 0x7fffu + ((v.u >> 16) & 1u);
    return (unsigned short)(r >> 16);
}
static __device__ __forceinline__ float blo(unsigned u) {
    union { unsigned u; float f; } v; v.u = u << 16; return v.f;
}
static __device__ __forceinline__ float bhi(unsigned u) {
    union { unsigned u; float f; } v; v.u = u & 0xffff0000u; return v.f;
}

// ---------------------------------------------------------------------------
// One-time prep: blocks 0..255 convert weights fp32->bf16; blocks 256..287
// compute qn_0 = (LN(query)*g+b) @ Wq^T * scale.
// ---------------------------------------------------------------------------
__global__ __launch_bounds__(256) void k_prep(
    const float* __restrict__ Wk, const float* __restrict__ Wv,
    const float* __restrict__ wih, const float* __restrict__ whh,
    const float* __restrict__ w1, const float* __restrict__ w2,
    unsigned short* __restrict__ Wk_bf, unsigned short* __restrict__ Wv_bf,
    unsigned short* __restrict__ wih_bf, unsigned short* __restrict__ whh_bf,
    unsigned short* __restrict__ w1_bf, unsigned short* __restrict__ w2_bf,
    const float* __restrict__ query, const float* __restrict__ lnqg,
    const float* __restrict__ lnqb, const float* __restrict__ Wq,
    unsigned short* __restrict__ qn_g)
{
    __shared__ __align__(16) float xq[16 * 128];
    int tid = threadIdx.x;
    if (blockIdx.x < 256) {
        int t = blockIdx.x * 256 + tid;
        const float* src; unsigned short* dst; int off;
        if (t < 4096)       { src = Wk;  dst = Wk_bf;  off = t; }
        else if (t < 8192)  { src = Wv;  dst = Wv_bf;  off = t - 4096; }
        else if (t < 20480) { src = wih; dst = wih_bf; off = t - 8192; }
        else if (t < 32768) { src = whh; dst = whh_bf; off = t - 20480; }
        else if (t < 49152) { src = w1;  dst = w1_bf;  off = t - 32768; }
        else                { src = w2;  dst = w2_bf;  off = t - 49152; }
        float4 a = ((const float4*)src)[off];
        uint2 p;
        p.x = (unsigned)f2b(a.x) | ((unsigned)f2b(a.y) << 16);
        p.y = (unsigned)f2b(a.z) | ((unsigned)f2b(a.w) << 16);
        *(uint2*)(dst + off * 4) = p;
        return;
    }
    int b = blockIdx.x - 256;
    int n = tid >> 4, part = tid & 15;
    int row = b * 16 + n;
    const float4* x4 = (const float4*)(query + row * 128 + part * 8);
    float4 x0 = x4[0], x1 = x4[1];
    float s = x0.x + x0.y + x0.z + x0.w + x1.x + x1.y + x1.z + x1.w;
    float ss = x0.x * x0.x + x0.y * x0.y + x0.z * x0.z + x0.w * x0.w +
               x1.x * x1.x + x1.y * x1.y + x1.z * x1.z + x1.w * x1.w;
    s += __shfl_xor(s, 1); s += __shfl_xor(s, 2); s += __shfl_xor(s, 4); s += __shfl_xor(s, 8);
    ss += __shfl_xor(ss, 1); ss += __shfl_xor(ss, 2); ss += __shfl_xor(ss, 4); ss += __shfl_xor(ss, 8);
    float mean = s * (1.f / 128.f);
    float var = ss * (1.f / 128.f) - mean * mean;
    float rstd = rsqrtf(var + EPS_LN);
    const float4* g4 = (const float4*)(lnqg + part * 8);
    const float4* b4 = (const float4*)(lnqb + part * 8);
    float4 g0 = g4[0], g1 = g4[1], bb0 = b4[0], bb1 = b4[1];
    float4 o0, o1;
    o0.x = (x0.x - mean) * rstd * g0.x + bb0.x;
    o0.y = (x0.y - mean) * rstd * g0.y + bb0.y;
    o0.z = (x0.z - mean) * rstd * g0.z + bb0.z;
    o0.w = (x0.w - mean) * rstd * g0.w + bb0.w;
    o1.x = (x1.x - mean) * rstd * g1.x + bb1.x;
    o1.y = (x1.y - mean) * rstd * g1.y + bb1.y;
    o1.z = (x1.z - mean) * rstd * g1.z + bb1.z;
    o1.w = (x1.w - mean) * rstd * g1.w + bb1.w;
    float4* xrow = (float4*)&xq[n * 128];
    xrow[part * 2] = o0;
    xrow[part * 2 + 1] = o1;
    __syncthreads();
    float o[8] = {0.f, 0.f, 0.f, 0.f, 0.f, 0.f, 0.f, 0.f};
    const float4* xv4 = (const float4*)&xq[n * 128];
#pragma unroll 4
    for (int j = 0; j < 32; j++) {
        float4 xv = xv4[j];
#pragma unroll
        for (int i = 0; i < 8; i++) {
            float4 w = ((const float4*)(Wq + (part * 8 + i) * 128))[j];
            o[i] += w.x * xv.x + w.y * xv.y + w.z * xv.z + w.w * xv.w;
        }
    }
    const float scale = 0.08838834764831845f;
#pragma unroll
    for (int i = 0; i < 8; i++)
        qn_g[row * 128 + part * 8 + i] = f2b(o[i] * scale);
}

// ---------------------------------------------------------------------------
// Kernel 1 (R4 proven version): kv = LN(inp); K -> [b][hw][c]; V -> [b][c][hw]
// 64 rows/block. In-register LN. XOR-swizzled W_lds. K staged [m][132],
// V staged transposed [c][70] for vectorized stores.
// ---------------------------------------------------------------------------
__global__ __launch_bounds__(256) void k_kvproj(
    const float* __restrict__ inp, const float* __restrict__ lng,
    const float* __restrict__ lnb, const unsigned short* __restrict__ Wk_bf,
    const unsigned short* __restrict__ Wv_bf, unsigned short* __restrict__ Kbf,
    unsigned short* __restrict__ Vt)
{
    __shared__ __align__(16) unsigned short W_lds[128 * 128];  // 32 KB
    __shared__ __align__(16) unsigned short T_lds[8960];       // 17.9 KB
    const int tid = threadIdx.x;
    const int wave = tid >> 6, lane = tid & 63;
    const int l15 = lane & 15, q4 = lane >> 4;
    const int kof = q4 * 8;
    const int tile0 = blockIdx.x * 64;
    const int b = tile0 >> 12;
    const int hwbase = tile0 & (HW_ - 1);

    const int srow = tid >> 1, shalf = tid & 1;
    const int sswz = srow & 7;

    // ---- in-register LN ----
    float x[4][8];
    {
        const float* rowp = inp + (tile0 + (wave << 4) + l15) * C_;
        float s = 0.f, ss = 0.f;
#pragma unroll
        for (int ks = 0; ks < 4; ks++) {
#pragma unroll
            for (int h = 0; h < 2; h++) {
                float4 v = *(const float4*)(rowp + ks * 32 + kof + h * 4);
                x[ks][h * 4 + 0] = v.x; x[ks][h * 4 + 1] = v.y;
                x[ks][h * 4 + 2] = v.z; x[ks][h * 4 + 3] = v.w;
                s += v.x + v.y + v.z + v.w;
                ss += v.x * v.x + v.y * v.y + v.z * v.z + v.w * v.w;
            }
        }
        s += __shfl_xor(s, 16);  s += __shfl_xor(s, 32);
        ss += __shfl_xor(ss, 16); ss += __shfl_xor(ss, 32);
        float mean = s * (1.f / 128.f);
        float var = ss * (1.f / 128.f) - mean * mean;
        float rstd = rsqrtf(var + EPS_LN);
#pragma unroll
        for (int ks = 0; ks < 4; ks++) {
#pragma unroll
            for (int h = 0; h < 2; h++) {
                float4 g = *(const float4*)(lng + ks * 32 + kof + h * 4);
                float4 bb = *(const float4*)(lnb + ks * 32 + kof + h * 4);
                x[ks][h * 4 + 0] = (x[ks][h * 4 + 0] - mean) * rstd * g.x + bb.x;
                x[ks][h * 4 + 1] = (x[ks][h * 4 + 1] - mean) * rstd * g.y + bb.y;
                x[ks][h * 4 + 2] = (x[ks][h * 4 + 2] - mean) * rstd * g.z + bb.z;
                x[ks][h * 4 + 3] = (x[ks][h * 4 + 3] - mean) * rstd * g.w + bb.w;
            }
        }
    }
    short8 af[4];
#pragma unroll
    for (int ks = 0; ks < 4; ks++) {
        union { short8 s8; unsigned u[4]; } p;
#pragma unroll
        for (int j = 0; j < 4; j++)
            p.u[j] = (unsigned)f2b(x[ks][2 * j]) | ((unsigned)f2b(x[ks][2 * j + 1]) << 16);
        af[ks] = p.s8;
    }

    // ---- stage Wk (swizzled) ----
    {
        const uint4* gW = (const uint4*)Wk_bf;
#pragma unroll
        for (int j = 0; j < 8; j++) {
            int c = shalf * 8 + j;
            uint4 w = gW[srow * 16 + c];
            *(uint4*)&W_lds[srow * 128 + (c ^ sswz) * 8] = w;
        }
    }
    __syncthreads();

    f32x4 acc[8];
    // ---- K phase ----
#pragma unroll
    for (int nt = 0; nt < 8; nt++) {
        acc[nt] = (f32x4){0.f, 0.f, 0.f, 0.f};
#pragma unroll
        for (int ks = 0; ks < 4; ks++) {
            short8 bf = *(const short8*)&W_lds[(nt * 16 + l15) * 128 + ((ks * 4 + q4) ^ (l15 & 7)) * 8];
            acc[nt] = __builtin_amdgcn_mfma_f32_16x16x32_bf16(af[ks], bf, acc[nt], 0, 0, 0);
        }
    }
    // K acc -> T [m][132]
#pragma unroll
    for (int nt = 0; nt < 8; nt++) {
        int c = nt * 16 + l15;
#pragma unroll
        for (int i = 0; i < 4; i++)
            T_lds[((wave << 4) + (q4 << 2) + i) * 132 + c] = f2b(acc[nt][i]);
    }
    __syncthreads();
    // K coalesced stores + stage Wv
    {
        int row = tid >> 2, part = tid & 3;
        uint4* dst = (uint4*)&Kbf[(b * HW_ + hwbase + row) * C_ + part * 32];
#pragma unroll
        for (int j = 0; j < 4; j++)
            dst[j] = *(const uint4*)&T_lds[row * 132 + part * 32 + j * 8];
    }
    {
        const uint4* gW = (const uint4*)Wv_bf;
#pragma unroll
        for (int j = 0; j < 8; j++) {
            int c = shalf * 8 + j;
            uint4 w = gW[srow * 16 + c];
            *(uint4*)&W_lds[srow * 128 + (c ^ sswz) * 8] = w;
        }
    }
    __syncthreads();
    // ---- V phase ----
#pragma unroll
    for (int nt = 0; nt < 8; nt++) {
        acc[nt] = (f32x4){0.f, 0.f, 0.f, 0.f};
#pragma unroll
        for (int ks = 0; ks < 4; ks++) {
            short8 bf = *(const short8*)&W_lds[(nt * 16 + l15) * 128 + ((ks * 4 + q4) ^ (l15 & 7)) * 8];
            acc[nt] = __builtin_amdgcn_mfma_f32_16x16x32_bf16(af[ks], bf, acc[nt], 0, 0, 0);
        }
    }
    __syncthreads();
    // V acc -> T2 transposed [c][70]
#pragma unroll
    for (int nt = 0; nt < 8; nt++) {
        int c = nt * 16 + l15;
#pragma unroll
        for (int i = 0; i < 4; i++)
            T_lds[c * 70 + (wave << 4) + (q4 << 2) + i] = f2b(acc[nt][i]);
    }
    __syncthreads();
    // V stores: vectorized from T2
    {
        int c = tid >> 1, half = tid & 1;
        uint4* dst = (uint4*)&Vt[(b * C_ + c) * HW_ + hwbase + half * 32];
#pragma unroll
        for (int j = 0; j < 4; j++)
            dst[j] = *(const uint4*)&T_lds[c * 70 + half * 32 + j * 8];
    }
}

// ---------------------------------------------------------------------------
// Kernel 2 (per iter): 128-thread blocks (2 waves), grid (32, B).
// Each wave: 64 hw -> 4 score tiles + column softmax + PV (2 k-chunks).
// Per-wave Ul[q][132] written as float4; export coalesced to Upart [q*128+c].
// ---------------------------------------------------------------------------
__global__ __launch_bounds__(128) void k_attn(
    const unsigned short* __restrict__ qn_g, const unsigned short* __restrict__ Kbf,
    const unsigned short* __restrict__ Vt, float* __restrict__ Upart,
    float* __restrict__ rspart, float* __restrict__ a0_out, int last)
{
    __shared__ __align__(16) float Ul[2][16 * 132];        // 16.9 KB
    __shared__ __align__(16) unsigned short Pb[2][16 * 72]; // 4.6 KB
    __shared__ float rsw[2][16];
    const int b = blockIdx.y, chunk = blockIdx.x;
    const int tid = threadIdx.x;
    const int wave = tid >> 6, lane = tid & 63;
    const int l15 = lane & 15, q4 = lane >> 4;
    const int kof = q4 * 8;
    const int hwb = chunk * 128 + wave * 64;

    short8 aq[4];
#pragma unroll
    for (int ks = 0; ks < 4; ks++)
        aq[ks] = *(const short8*)&qn_g[(b * 16 + l15) * 128 + ks * 32 + kof];
    // preload PV A-fragments early (independent of score chain)
    short8 av[8][2];
#pragma unroll
    for (int ct = 0; ct < 8; ct++) {
#pragma unroll
        for (int k2 = 0; k2 < 2; k2++)
            av[ct][k2] = *(const short8*)&Vt[(b * C_ + ct * 16 + l15) * HW_ + hwb + k2 * 32 + kof];
    }

    unsigned short* Pw = &Pb[wave][0];
    float rs[4] = {0.f, 0.f, 0.f, 0.f};
#pragma unroll
    for (int s = 0; s < 4; s++) {
        int hwt = hwb + s * 16;
        f32x4 sa = {0.f, 0.f, 0.f, 0.f};
#pragma unroll
        for (int ks = 0; ks < 4; ks++) {
            short8 bk = *(const short8*)&Kbf[(b * HW_ + hwt + l15) * C_ + ks * 32 + kof];
            sa = __builtin_amdgcn_mfma_f32_16x16x32_bf16(aq[ks], bk, sa, 0, 0, 0);
        }
        float mx = fmaxf(fmaxf(sa[0], sa[1]), fmaxf(sa[2], sa[3]));
        mx = fmaxf(mx, __shfl_xor(mx, 16));
        mx = fmaxf(mx, __shfl_xor(mx, 32));
        float e[4]; float ssum = 0.f;
#pragma unroll
        for (int i = 0; i < 4; i++) { e[i] = __expf(sa[i] - mx); ssum += e[i]; }
        ssum += __shfl_xor(ssum, 16);
        ssum += __shfl_xor(ssum, 32);
        float inv = 1.f / ssum;
#pragma unroll
        for (int i = 0; i < 4; i++) {
            float a0v = e[i] * inv;
            rs[i] += a0v;
            if (last) a0_out[(b * 16 + q4 * 4 + i) * HW_ + hwt + l15] = a0v;
            Pw[(q4 * 4 + i) * 72 + s * 16 + l15] = f2b(a0v);
        }
    }
    // rowsum (sum over this wave's 64 hw)
#pragma unroll
    for (int i = 0; i < 4; i++) {
        rs[i] += __shfl_xor(rs[i], 1);
        rs[i] += __shfl_xor(rs[i], 2);
        rs[i] += __shfl_xor(rs[i], 4);
        rs[i] += __shfl_xor(rs[i], 8);
    }
    if (l15 == 0) {
#pragma unroll
        for (int i = 0; i < 4; i++) rsw[wave][q4 * 4 + i] = rs[i];
    }
    // PV: same-wave P read (compiler inserts lgkmcnt; P is wave-private)
    short8 bp0 = *(const short8*)&Pw[l15 * 72 + kof];
    short8 bp1 = *(const short8*)&Pw[l15 * 72 + 32 + kof];
#pragma unroll
    for (int ct = 0; ct < 8; ct++) {
        f32x4 ua = __builtin_amdgcn_mfma_f32_16x16x32_bf16(av[ct][0], bp0, (f32x4){0.f, 0.f, 0.f, 0.f}, 0, 0, 0);
        ua = __builtin_amdgcn_mfma_f32_16x16x32_bf16(av[ct][1], bp1, ua, 0, 0, 0);
        // lane holds q = l15, c = ct*16 + q4*4 + i (i contiguous) -> float4 store
        *(f32x4*)&Ul[wave][l15 * 132 + ct * 16 + (q4 << 2)] = ua;
    }
    __syncthreads();
    // export: Upart layout [q*128 + c], fully coalesced
    {
        float* up = Upart + (b * 32 + chunk) * 2048;
#pragma unroll
        for (int k = 0; k < 16; k++) {
            int idx = tid + k * 128;          // idx = q*128 + c
            int q = idx >> 7, c = idx & 127;
            up[idx] = Ul[0][q * 132 + c] + Ul[1][q * 132 + c];
        }
        if (tid < 16)
            rspart[(b * 32 + chunk) * 16 + tid] = rsw[0][tid] + rsw[1][tid];
    }
}

// ---------------------------------------------------------------------------
// Kernel 3 (per iter): one (b,q) row per block, 256 threads.
// u = (sum Upart)/(sum rspart + eps); y = GRU(u, h); z = LN2(y);
// q_new = y + FFN(z); if !last: qn_next = LN(q_new)@Wq^T*scale.
// ---------------------------------------------------------------------------
__global__ __launch_bounds__(256) void k_tail(
    const float* __restrict__ Upart, const float* __restrict__ rspart,
    const float* __restrict__ hsrc, float* __restrict__ q_buf,
    const unsigned short* __restrict__ wih_bf, const unsigned short* __restrict__ whh_bf,
    const float* __restrict__ bih, const float* __restrict__ bhh,
    const float* __restrict__ ln2g, const float* __restrict__ ln2b,
    const unsigned short* __restrict__ w1_bf, const float* __restrict__ b1,
    const unsigned short* __restrict__ w2_bf, const float* __restrict__ b2,
    const float* __restrict__ lnqg, const float* __restrict__ lnqb,
    const float* __restrict__ Wq, unsigned short* __restrict__ qn_g,
    float* __restrict__ out_q, int last)
{
    __shared__ __align__(16) float u_l[128];
    __shared__ __align__(16) float h_l[128];
    __shared__ __align__(16) float g_l[768];
    __shared__ __align__(16) float z_l[128];
    __shared__ __align__(16) float y_l[128];
    __shared__ __align__(16) float h1_l[512];
    __shared__ __align__(16) float red[256];
    __shared__ float stats[2];
    __shared__ float srs;
    const int tid = threadIdx.x;
    const int row = blockIdx.x;
    const int b = row >> 4, q = row & 15;
    const int lane = tid & 63;

    // coalesced Upart reduce (layout [q*128+c])
    {
        int c = tid & 127, h = tid >> 7;
        float part = 0.f;
#pragma unroll
        for (int ch = 0; ch < 16; ch++)
            part += Upart[(b * 32 + h * 16 + ch) * 2048 + q * 128 + c];
        red[tid] = part;
        if (tid < 128) h_l[tid] = hsrc[row * 128 + tid];
        if (tid < 64) {
            float v = (lane < 32) ? rspart[(b * 32 + lane) * 16 + q] : 0.f;
#pragma unroll
            for (int off = 1; off < 64; off <<= 1) v += __shfl_xor(v, off);
            if (tid == 0) srs = v;
        }
    }
    __syncthreads();
    if (tid < 128)
        u_l[tid] = (red[tid] + red[tid + 128]) / (srs + EPS_ATTN);
    __syncthreads();
    // GRU gates: 768 outputs, 3 per thread
#pragma unroll
    for (int o3 = 0; o3 < 3; o3++) {
        int o = tid + o3 * 256;
        const unsigned short* wrow;
        const float* src;
        float bias;
        if (o < 384) { wrow = wih_bf + o * 128; src = u_l; bias = bih[o]; }
        else         { wrow = whh_bf + (o - 384) * 128; src = h_l; bias = bhh[o - 384]; }
        const uint4* w4 = (const uint4*)wrow;
        const float4* s4 = (const float4*)src;
        float acc = 0.f;
#pragma unroll 8
        for (int j = 0; j < 16; j++) {
            uint4 w = w4[j];
            float4 aA = s4[2 * j], aB = s4[2 * j + 1];
            acc += blo(w.x) * aA.x + bhi(w.x) * aA.y + blo(w.y) * aA.z + bhi(w.y) * aA.w
                 + blo(w.z) * aB.x + bhi(w.z) * aB.y + blo(w.w) * aB.z + bhi(w.w) * aB.w;
        }
        g_l[o] = acc + bias;
    }
    __syncthreads();
    if (tid < 128) {
        int c = tid;
        float ir = g_l[c], iz = g_l[128 + c], in_ = g_l[256 + c];
        float hr = g_l[384 + c], hz = g_l[512 + c], hn = g_l[640 + c];
        float rr = 1.f / (1.f + expf(-(ir + hr)));
        float zz = 1.f / (1.f + expf(-(iz + hz)));
        float nn = tanhf(in_ + rr * hn);
        y_l[c] = (1.f - zz) * nn + zz * h_l[c];
    }
    __syncthreads();
    if (tid < 64) {
        float v0 = y_l[lane], v1 = y_l[lane + 64];
        float s = v0 + v1, ss = v0 * v0 + v1 * v1;
#pragma unroll
        for (int off = 1; off < 64; off <<= 1) {
            s += __shfl_xor(s, off);
            ss += __shfl_xor(ss, off);
        }
        if (tid == 0) {
            float mean = s * (1.f / 128.f);
            float var = ss * (1.f / 128.f) - mean * mean;
            stats[0] = mean;
            stats[1] = rsqrtf(var + EPS_LN);
        }
    }
    __syncthreads();
    if (tid < 128)
        z_l[tid] = (y_l[tid] - stats[0]) * stats[1] * ln2g[tid] + ln2b[tid];
    __syncthreads();
    // FFN1: 512 outputs, 2 per thread
#pragma unroll
    for (int f2i = 0; f2i < 2; f2i++) {
        int f = tid + f2i * 256;
        const uint4* w4 = (const uint4*)(w1_bf + f * 128);
        const float4* s4 = (const float4*)z_l;
        float acc = 0.f;
#pragma unroll 8
        for (int j = 0; j < 16; j++) {
            uint4 w = w4[j];
            float4 aA = s4[2 * j], aB = s4[2 * j + 1];
            acc += blo(w.x) * aA.x + bhi(w.x) * aA.y + blo(w.y) * aA.z + bhi(w.y) * aA.w
                 + blo(w.z) * aB.x + bhi(w.z) * aB.y + blo(w.w) * aB.z + bhi(w.w) * aB.w;
        }
        h1_l[f] = fmaxf(acc + b1[f], 0.f);
    }
    __syncthreads();
    // FFN2: thread (c = tid&127, h = tid>>7) computes half the 512-dot
    {
        int c = tid & 127, h = tid >> 7;
        const uint4* w4 = (const uint4*)(w2_bf + c * 512 + h * 256);
        const float4* hh = (const float4*)&h1_l[h * 256];
        float acc = 0.f;
#pragma unroll 8
        for (int j = 0; j < 32; j++) {
            uint4 w = w4[j];
            float4 hA = hh[2 * j], hB = hh[2 * j + 1];
            acc += blo(w.x) * hA.x + bhi(w.x) * hA.y + blo(w.y) * hA.z + bhi(w.y) * hA.w
                 + blo(w.z) * hB.x + bhi(w.z) * hB.y + blo(w.w) * hB.z + bhi(w.w) * hB.w;
        }
        red[tid] = acc;
    }
    __syncthreads();
    float q_new = 0.f;
    if (tid < 128) {
        q_new = y_l[tid] + red[tid] + red[tid + 128] + b2[tid];
        q_buf[row * 128 + tid] = q_new;
        if (last) out_q[row * 128 + tid] = q_new;
    }
    if (!last) {
        __syncthreads();
        if (tid < 128) y_l[tid] = q_new;
        __syncthreads();
        if (tid < 64) {
            float v0 = y_l[lane], v1 = y_l[lane + 64];
            float s = v0 + v1, ss = v0 * v0 + v1 * v1;
#pragma unroll
            for (int off = 1; off < 64; off <<= 1) {
                s += __shfl_xor(s, off);
                ss += __shfl_xor(ss, off);
            }
            if (tid == 0) {
                float mean = s * (1.f / 128.f);
                float var = ss * (1.f / 128.f) - mean * mean;
                stats[0] = mean;
                stats[1] = rsqrtf(var + EPS_LN);
            }
        }
        __syncthreads();
        if (tid < 128)
            z_l[tid] = (y_l[tid] - stats[0]) * stats[1] * lnqg[tid] + lnqb[tid];
        __syncthreads();
        {
            int c = tid & 127, h = tid >> 7;
            const float4* w4 = (const float4*)(Wq + c * 128 + h * 64);
            const float4* zz = (const float4*)&z_l[h * 64];
            float acc = 0.f;
#pragma unroll 8
            for (int j = 0; j < 16; j++) {
                float4 w = w4[j], v = zz[j];
                acc += w.x * v.x + w.y * v.y + w.z * v.z + w.w * v.w;
            }
            red[tid] = acc;
        }
        __syncthreads();
        if (tid < 128)
            qn_g[row * 128 + tid] = f2b((red[tid] + red[tid + 128]) * 0.08838834764831845f);
    }
}

// ---------------------------------------------------------------------------
extern "C" void kernel_launch(void* const* d_in, const int* in_sizes, int n_in,
                              void* d_out, int out_size, void* d_ws, size_t ws_size,
                              hipStream_t stream) {
    const float* inp     = (const float*)d_in[0];
    const float* query   = (const float*)d_in[1];
    const float* ln_kv_g = (const float*)d_in[2];
    const float* ln_kv_b = (const float*)d_in[3];
    const float* Wk      = (const float*)d_in[4];
    const float* Wv      = (const float*)d_in[5];
    const float* ln_q_g  = (const float*)d_in[6];
    const float* ln_q_b  = (const float*)d_in[7];
    const float* Wq      = (const float*)d_in[8];
    const float* gru_wih = (const float*)d_in[9];
    const float* gru_whh = (const float*)d_in[10];
    const float* gru_bih = (const float*)d_in[11];
    const float* gru_bhh = (const float*)d_in[12];
    const float* ln2_g   = (const float*)d_in[13];
    const float* ln2_b   = (const float*)d_in[14];
    const float* ffn_w1  = (const float*)d_in[15];
    const float* ffn_b1  = (const float*)d_in[16];
    const float* ffn_w2  = (const float*)d_in[17];
    const float* ffn_b2  = (const float*)d_in[18];

    char* ws = (char*)d_ws;
    unsigned short* Kbf    = (unsigned short*)ws;                  // 33554432
    unsigned short* Vt     = (unsigned short*)(ws + 33554432);     // 33554432
    float* q_buf           = (float*)(ws + 67108864);              // 262144
    float* Upart           = (float*)(ws + 67371008);              // 8388608
    float* rspart          = (float*)(ws + 75759616);              // 65536
    unsigned short* qn_g   = (unsigned short*)(ws + 75825152);     // 131072
    unsigned short* Wk_bf  = (unsigned short*)(ws + 75956224);     // 32768
    unsigned short* Wv_bf  = (unsigned short*)(ws + 75988992);     // 32768
    unsigned short* wih_bf = (unsigned short*)(ws + 76021760);     // 98304
    unsigned short* whh_bf = (unsigned short*)(ws + 76120064);     // 98304
    unsigned short* w1_bf  = (unsigned short*)(ws + 76218368);     // 131072
    unsigned short* w2_bf  = (unsigned short*)(ws + 76349440);     // 131072

    float* out_q  = (float*)d_out;
    float* out_a0 = out_q + B_ * N_ * C_;

    k_prep<<<dim3(288), dim3(256), 0, stream>>>(
        Wk, Wv, gru_wih, gru_whh, ffn_w1, ffn_w2,
        Wk_bf, Wv_bf, wih_bf, whh_bf, w1_bf, w2_bf,
        query, ln_q_g, ln_q_b, Wq, qn_g);
    k_kvproj<<<dim3((B_ * HW_) / 64), dim3(256), 0, stream>>>(
        inp, ln_kv_g, ln_kv_b, Wk_bf, Wv_bf, Kbf, Vt);

    for (int it = 0; it < ITERS_; it++) {
        int last = (it == ITERS_ - 1) ? 1 : 0;
        const float* hsrc = (it == 0) ? query : q_buf;
        k_attn<<<dim3(32, B_), dim3(128), 0, stream>>>(
            qn_g, Kbf, Vt, Upart, rspart, out_a0, last);
        k_tail<<<dim3(B_ * N_), dim3(256), 0, stream>>>(
            Upart, rspart, hsrc, q_buf, wih_bf, whh_bf, gru_bih, gru_bhh,
            ln2_g, ln2_b, w1_bf, ffn_b1, w2_bf, ffn_b2,
            ln_q_g, ln_q_b, Wq, qn_g, out_q, last);
    }
}